// Round 8
// baseline (988.085 us; speedup 1.0000x reference)
//
#include <hip/hip_runtime.h>
#include <math.h>

#define NEGF -1000000000.0f
#define EPSF 1e-7f

// B=32, T=256, IN=64, H=128, 4H=512, TOP_K=5

typedef float v4f __attribute__((ext_vector_type(4)));
#define FMA4(a, b, c) __builtin_elementwise_fma((a), (b), (c))

// Raw barrier: LDS-only drain + s_barrier (keeps global prefetch in flight).
#define RAWBAR() asm volatile("s_waitcnt lgkmcnt(0)\n\ts_barrier" ::: "memory")

__device__ __forceinline__ float fsigmoid(float x) {
  return 1.0f / (1.0f + __expf(-x));               // overflow -> correct limit
}
__device__ __forceinline__ float ftanh(float x) {
  return 1.0f - 2.0f / (1.0f + __expf(2.0f * x));  // limits +-1: correct
}

// wave64 all-reduce sum via DPP (row_shr 1/2/4/8 + row_bcast 15/31), ~35 cyc.
__device__ __forceinline__ float wave_allsum(float v) {
#if __has_builtin(__builtin_amdgcn_update_dpp) && __has_builtin(__builtin_amdgcn_readlane)
  float f = v;
#define DPPSTEP(ctrl, rmask) { \
    int t = __builtin_amdgcn_update_dpp(0, __builtin_bit_cast(int, f), \
                                        ctrl, rmask, 0xf, true); \
    f += __builtin_bit_cast(float, t); }
  DPPSTEP(0x111, 0xf)   // row_shr:1
  DPPSTEP(0x112, 0xf)   // row_shr:2
  DPPSTEP(0x114, 0xf)   // row_shr:4
  DPPSTEP(0x118, 0xf)   // row_shr:8  -> lane15 of each row has row sum
  DPPSTEP(0x142, 0xa)   // row_bcast:15 into rows 1,3
  DPPSTEP(0x143, 0x8)   // row_bcast:31 into row 3 -> lane 63 = total
#undef DPPSTEP
  return __builtin_bit_cast(float,
      __builtin_amdgcn_readlane(__builtin_bit_cast(int, f), 63));
#else
  for (int off = 1; off < 64; off <<= 1) v += __shfl_xor(v, off, 64);
  return v;
#endif
}

// Kernel 1: xw[b][t][g] = x[b][t] . W_ih[g] + (b_ih[g]+b_hh[g])
// EXACT round-3/5 version (best measured two-kernel total).
__global__ __launch_bounds__(512) void xw_kernel(
    const float* __restrict__ x, const float* __restrict__ W_ih,
    const float* __restrict__ b_ih, const float* __restrict__ b_hh,
    float* __restrict__ xw)
{
  const int t0 = blockIdx.x * 32;
  const int b  = blockIdx.y;
  const int g  = threadIdx.x;

  __shared__ float sx[32 * 64];              // 8 KB
  ((float4*)sx)[threadIdx.x] =
      ((const float4*)(x + (size_t)(b * 256 + t0) * 64))[threadIdx.x];

  const float4* wr = (const float4*)(W_ih + (size_t)g * 64);
  float4 w0 = wr[0],  w1 = wr[1],  w2 = wr[2],  w3 = wr[3],
         w4 = wr[4],  w5 = wr[5],  w6 = wr[6],  w7 = wr[7],
         w8 = wr[8],  w9 = wr[9],  w10 = wr[10], w11 = wr[11],
         w12 = wr[12], w13 = wr[13], w14 = wr[14], w15 = wr[15];
  const float bias = b_ih[g] + b_hh[g];
  __syncthreads();

  float* dst = xw + (size_t)(b * 256 + t0) * 512 + g;
  for (int tt = 0; tt < 32; ++tt) {
    const float4* xr = (const float4*)(sx + tt * 64);
    float a0 = 0.0f, a1 = 0.0f, a2 = 0.0f, a3 = 0.0f;
#define XSTEP(j) { float4 hv = xr[j]; \
    a0 = fmaf(w##j.x, hv.x, a0); a1 = fmaf(w##j.y, hv.y, a1); \
    a2 = fmaf(w##j.z, hv.z, a2); a3 = fmaf(w##j.w, hv.w, a3); }
    XSTEP(0) XSTEP(1) XSTEP(2) XSTEP(3) XSTEP(4) XSTEP(5) XSTEP(6) XSTEP(7)
    XSTEP(8) XSTEP(9) XSTEP(10) XSTEP(11) XSTEP(12) XSTEP(13) XSTEP(14) XSTEP(15)
#undef XSTEP
    dst[(size_t)tt * 512] = (a0 + a1) + (a2 + a3) + bias;
  }
}

// Kernel 2: full recurrence, one block per batch element, 1024 threads.
// Round-1/5 skeleton with two issue-cutting changes (the kernel is
// VALU-issue + serial-PhaseB bound at the ~1.1GHz effective clock of a
// 32-CU dispatch; KEEP4 null + FETCH_SIZE proved weights were always
// resident (AGPRs, VGPR_Count=64 counts arch VGPRs only)):
//  1. Phase A W_hh dot in packed fp32 (v_pk_fma_f32): 64 scalar FMA ->
//     16 pk-FMA per thread (issue 640 -> ~320 cyc/SIMD/step).
//  2. Gate partials combined with LDS ds_add_f32 into double-buffered
//     sh_part[2][512] (buf (i&1) zeroed two steps ahead in wave0's tail);
//     Phase B's 16-read GSUM tree -> 4 b64 reads.
//
// DELTA CANCELLATION (unchanged):
//   s[t] = a + d[t]; delta = a + top5(d)[4] + EPS  =>  w[t] = d[t]-t5v4-EPS
//   independent of a. Sparse attention = 4 register-indexed LDS row gathers
//   whose addresses are known from the PREVIOUS step (prefetched before S1).
//   Raw-score path (rem<=5) kept as a 5-step special case.
__global__
__attribute__((amdgpu_flat_work_group_size(1024, 1024), amdgpu_waves_per_eu(4, 4)))
void lstm_attn(
    const float* __restrict__ xw, const float* __restrict__ W_hh,
    const float* __restrict__ w_t, float* __restrict__ out)
{
  const int b   = blockIdx.x;
  const int tid = threadIdx.x;
  const int l   = tid & 63;       // lane
  const int wid = tid >> 6;
  const int p   = tid & 255;      // gate-pair id
  const int q   = tid >> 8;       // K-chunk 0..3 (wave-uniform)
  const int gA  = p;
  const int gB  = p + 256;

  __shared__ float ho[257 * 128];     // fp32 h history (131584 B)
  __shared__ float sh_part[2][512];   // ds_add-reduced gate sums, dbuf (4 KB)
  __shared__ float sh_d[8];           // d[t] cache, only needed for t<5

  // one-time weight load: 16 named v4f (resident in unified VGPR/AGPR file)
  const v4f* pA = (const v4f*)(W_hh + (size_t)gA * 128 + (q << 5));
  const v4f* pB = (const v4f*)(W_hh + (size_t)gB * 128 + (q << 5));
  v4f wA0 = pA[0], wA1 = pA[1], wA2 = pA[2], wA3 = pA[3],
      wA4 = pA[4], wA5 = pA[5], wA6 = pA[6], wA7 = pA[7];
  v4f wB0 = pB[0], wB1 = pB[1], wB2 = pB[2], wB3 = pB[3],
      wB4 = pB[4], wB5 = pB[5], wB6 = pB[6], wB7 = pB[7];

  // wave0 per-lane persistent state (h elements j0=2l, j1=2l+1)
  const int j0 = 2 * l, j1 = 2 * l + 1;
  float c0 = 0.0f, c1 = 0.0f;
  float wa0 = 0.0f, wa1 = 0.0f, wb0 = 0.0f, wb1 = 0.0f;
  // running top-5 of d with indices (replicated identically in all wave0 lanes)
  float t5v0 = 0.0f, t5v1 = NEGF, t5v2 = NEGF, t5v3 = NEGF, t5v4 = NEGF;
  int   t5i0 = 0, t5i1 = 0, t5i2 = 0, t5i3 = 0;
  // precomputed (at end of step i-1) normalized gather weights + LDS offsets
  float gn0 = 0.0f, gn1 = 0.0f, gn2 = 0.0f, gn3 = 0.0f;
  int   ofs0 = 0, ofs1 = 0, ofs2 = 0, ofs3 = 0;

  if (wid == 0) {
    wa0 = w_t[j0];       wa1 = w_t[j1];
    wb0 = w_t[128 + j0]; wb1 = w_t[128 + j1];
    *(float2*)(ho + j0) = make_float2(0.0f, 0.0f);   // h(-1) = 0 (row 0)
    __builtin_amdgcn_s_setprio(1);   // wave0 is always the barrier straggler
  }
  ((float*)sh_part)[tid] = 0.0f;     // zero both buffers (1024 floats)
  if (tid == 0) sh_d[0] = 0.0f;
  __syncthreads();   // one-time full sync

  const float* xwb = xw + (size_t)b * 256 * 512;
  float xcurA = 0.0f, xcurB = 0.0f;
  if (q == 0) { xcurA = xwb[gA]; xcurB = xwb[gB]; }

  for (int i = 0; i < 256; ++i) {
    const int rem = i + 1;
    float hn0 = 0.0f, hn1 = 0.0f;
    float* shp = sh_part[i & 1];

    // ---- Phase A: gate partials (16 packed-fp32 FMAs) + ds_add reduce ----
    v4f accA = {xcurA, 0.0f, 0.0f, 0.0f};
    v4f accB = {xcurB, 0.0f, 0.0f, 0.0f};
    if (q == 0 && i < 255) {          // prefetch next step's xw (stays in
      xcurA = xwb[(size_t)(i + 1) * 512 + gA];   // flight across RAWBARs)
      xcurB = xwb[(size_t)(i + 1) * 512 + gB];
    }
    const v4f* hh4 = (const v4f*)(ho + i * 128 + (q << 5));
#define LSTEP(j) { v4f hv = hh4[j]; \
    accA = FMA4(wA##j, hv, accA); accB = FMA4(wB##j, hv, accB); }
    LSTEP(0) LSTEP(1) LSTEP(2) LSTEP(3) LSTEP(4) LSTEP(5) LSTEP(6) LSTEP(7)
#undef LSTEP
    atomicAdd(&shp[gA], (accA.x + accA.y) + (accA.z + accA.w));
    atomicAdd(&shp[gB], (accB.x + accB.y) + (accB.z + accB.w));

    // gather prefetch: addresses known from previous step's top-5; ho rows
    // are append-only so reading before the barrier is race-free.
    float2 hv0, hv1, hv2, hv3;
    if (wid == 0 && i >= 5) {
      hv0 = *(const float2*)(ho + ofs0);
      hv1 = *(const float2*)(ho + ofs1);
      hv2 = *(const float2*)(ho + ofs2);
      hv3 = *(const float2*)(ho + ofs3);
    }
    RAWBAR();                                             // S1

    if (wid == 0) {
      // ---- Phase B: LSTM cell (2 elements/lane), pre-reduced partials ----
      float2 Pi = *(const float2*)(shp + j0);
      float2 Pf = *(const float2*)(shp + 128 + j0);
      float2 Pg = *(const float2*)(shp + 256 + j0);
      float2 Po = *(const float2*)(shp + 384 + j0);
      c0 = fsigmoid(Pf.x) * c0 + fsigmoid(Pi.x) * ftanh(Pg.x);
      c1 = fsigmoid(Pf.y) * c1 + fsigmoid(Pi.y) * ftanh(Pg.y);
      float hc0 = fsigmoid(Po.x) * ftanh(c0);
      float hc1 = fsigmoid(Po.y) * ftanh(c1);

      float at0, at1;
      if (i >= 5) {
        // ---- sparse attention: 4 pre-fetched rows, register weights ----
        at0 = gn0 * hv0.x;            at1 = gn0 * hv0.y;
        at0 = fmaf(gn1, hv1.x, at0);  at1 = fmaf(gn1, hv1.y, at1);
        at0 = fmaf(gn2, hv2.x, at0);  at1 = fmaf(gn2, hv2.y, at1);
        at0 = fmaf(gn3, hv3.x, at0);  at1 = fmaf(gn3, hv3.y, at1);
      } else {
        // ---- rem<=5: attn weights are RAW scores s = a + d[t], no norm ----
        float a = wave_allsum(ftanh(hc0) * wa0 + ftanh(hc1) * wa1);
        at0 = 0.0f; at1 = 0.0f;
        for (int t = 0; t <= i; ++t) {
          float s = a + sh_d[t];
          float2 hv = *(const float2*)(ho + t * 128 + j0);
          at0 = fmaf(s, hv.x, at0);
          at1 = fmaf(s, hv.y, at1);
        }
      }
      hn0 = hc0 + at0; hn1 = hc1 + at1;
      *(float2*)(ho + rem * 128 + j0) = make_float2(hn0, hn1);
      if (i == 255) {
        out[b * 128 + j0] = at0; out[b * 128 + j1] = at1;   // attn_c
        // attn_w: zero except at the <=4 above-threshold top-5 indices
        #pragma unroll
        for (int m = 0; m < 4; ++m) {
          int t = l + 64 * m;
          float val = 0.0f;
          if (t == t5i0) val = gn0;
          if (t == t5i1) val = gn1;
          if (t == t5i2) val = gn2;
          if (t == t5i3) val = gn3;
          out[4096 + b * 256 + t] = val;
        }
      }
    }
    RAWBAR();                                             // S2

    // ---- tail (off critical path: overlaps other waves' next Phase A) ----
    if (wid == 0 && i < 255) {
      // zero the just-consumed buffer for step i+2 (safe: no other wave
      // touches buf[i&1] until Phase A of i+2, which is after S2(i+1),
      // which is after wave0's S1(i+1) arrival, which is after this tail)
      *(float4*)(&sh_part[i & 1][l << 3])       = make_float4(0.f, 0.f, 0.f, 0.f);
      *(float4*)(&sh_part[i & 1][(l << 3) + 4]) = make_float4(0.f, 0.f, 0.f, 0.f);
      float dn = wave_allsum(ftanh(hn0) * wb0 + ftanh(hn1) * wb1);
      if (l == 0 && i < 4) sh_d[rem] = dn;   // only raw-score steps read it
      // replicated top-5 (value,index) insert — identical in every lane
      float v = dn; int vi = rem;
      if (v > t5v0) { float tv = t5v0; int ti = t5i0; t5v0 = v; t5i0 = vi; v = tv; vi = ti; }
      if (v > t5v1) { float tv = t5v1; int ti = t5i1; t5v1 = v; t5i1 = vi; v = tv; vi = ti; }
      if (v > t5v2) { float tv = t5v2; int ti = t5i2; t5v2 = v; t5i2 = vi; v = tv; vi = ti; }
      if (v > t5v3) { float tv = t5v3; int ti = t5i3; t5v3 = v; t5i3 = vi; v = tv; vi = ti; }
      if (v > t5v4) { t5v4 = v; }
      // next step's normalized gather weights + offsets (delta cancellation:
      // w[t] = d[t] - t5v4 - EPS, nonzero only among top-4)
      float g0 = fmaxf(t5v0 - t5v4 - EPSF, 0.0f);
      float g1 = fmaxf(t5v1 - t5v4 - EPSF, 0.0f);
      float g2 = fmaxf(t5v2 - t5v4 - EPSF, 0.0f);
      float g3 = fmaxf(t5v3 - t5v4 - EPSF, 0.0f);
      float inv = 1.0f / (((g0 + g1) + (g2 + g3)) + EPSF);
      gn0 = g0 * inv; gn1 = g1 * inv; gn2 = g2 * inv; gn3 = g3 * inv;
      ofs0 = (t5i0 << 7) + j0; ofs1 = (t5i1 << 7) + j0;
      ofs2 = (t5i2 << 7) + j0; ofs3 = (t5i3 << 7) + j0;
    }
  }
}

extern "C" void kernel_launch(void* const* d_in, const int* in_sizes, int n_in,
                              void* d_out, int out_size, void* d_ws, size_t ws_size,
                              hipStream_t stream) {
  const float* x    = (const float*)d_in[0];  // (32,256,64)
  const float* W_ih = (const float*)d_in[1];  // (512,64)
  const float* W_hh = (const float*)d_in[2];  // (512,128)
  const float* b_ih = (const float*)d_in[3];  // (512,)
  const float* b_hh = (const float*)d_in[4];  // (512,)
  const float* w_t  = (const float*)d_in[5];  // (256,1)
  float* out = (float*)d_out;                 // [0:4096) attn_c, [4096:12288) attn_w

  float* xw = (float*)d_ws;                   // 32*256*512 fp32 = 16 MB

  xw_kernel<<<dim3(8, 32), 512, 0, stream>>>(x, W_ih, b_ih, b_hh, xw);
  lstm_attn<<<dim3(32), 1024, 0, stream>>>(xw, W_hh, w_t, out);
}

// Round 9
// 686.947 us; speedup vs baseline: 1.4384x; 1.4384x over previous
//
#include <hip/hip_runtime.h>
#include <math.h>

#define NEGF -1000000000.0f
#define EPSF 1e-7f

// B=32, T=256, IN=64, H=128, 4H=512, TOP_K=5

// Raw barrier: LDS-only drain + s_barrier (keeps global prefetch in flight).
#define RAWBAR() asm volatile("s_waitcnt lgkmcnt(0)\n\ts_barrier" ::: "memory")

__device__ __forceinline__ float fsigmoid(float x) {
  return 1.0f / (1.0f + __expf(-x));               // overflow -> correct limit
}
__device__ __forceinline__ float ftanh(float x) {
  return 1.0f - 2.0f / (1.0f + __expf(2.0f * x));  // limits +-1: correct
}

// wave64 all-reduce sum via DPP (row_shr 1/2/4/8 + row_bcast 15/31), ~35 cyc.
__device__ __forceinline__ float wave_allsum(float v) {
#if __has_builtin(__builtin_amdgcn_update_dpp) && __has_builtin(__builtin_amdgcn_readlane)
  float f = v;
#define DPPSTEP(ctrl, rmask) { \
    int t = __builtin_amdgcn_update_dpp(0, __builtin_bit_cast(int, f), \
                                        ctrl, rmask, 0xf, true); \
    f += __builtin_bit_cast(float, t); }
  DPPSTEP(0x111, 0xf)   // row_shr:1
  DPPSTEP(0x112, 0xf)   // row_shr:2
  DPPSTEP(0x114, 0xf)   // row_shr:4
  DPPSTEP(0x118, 0xf)   // row_shr:8  -> lane15 of each row has row sum
  DPPSTEP(0x142, 0xa)   // row_bcast:15 into rows 1,3
  DPPSTEP(0x143, 0x8)   // row_bcast:31 into row 3 -> lane 63 = total
#undef DPPSTEP
  return __builtin_bit_cast(float,
      __builtin_amdgcn_readlane(__builtin_bit_cast(int, f), 63));
#else
  for (int off = 1; off < 64; off <<= 1) v += __shfl_xor(v, off, 64);
  return v;
#endif
}

// Kernel 1: xw[b][t][g] = x[b][t] . W_ih[g] + (b_ih[g]+b_hh[g])
// EXACT round-3/5 version.
__global__ __launch_bounds__(512) void xw_kernel(
    const float* __restrict__ x, const float* __restrict__ W_ih,
    const float* __restrict__ b_ih, const float* __restrict__ b_hh,
    float* __restrict__ xw)
{
  const int t0 = blockIdx.x * 32;
  const int b  = blockIdx.y;
  const int g  = threadIdx.x;

  __shared__ float sx[32 * 64];              // 8 KB
  ((float4*)sx)[threadIdx.x] =
      ((const float4*)(x + (size_t)(b * 256 + t0) * 64))[threadIdx.x];

  const float4* wr = (const float4*)(W_ih + (size_t)g * 64);
  float4 w0 = wr[0],  w1 = wr[1],  w2 = wr[2],  w3 = wr[3],
         w4 = wr[4],  w5 = wr[5],  w6 = wr[6],  w7 = wr[7],
         w8 = wr[8],  w9 = wr[9],  w10 = wr[10], w11 = wr[11],
         w12 = wr[12], w13 = wr[13], w14 = wr[14], w15 = wr[15];
  const float bias = b_ih[g] + b_hh[g];
  __syncthreads();

  float* dst = xw + (size_t)(b * 256 + t0) * 512 + g;
  for (int tt = 0; tt < 32; ++tt) {
    const float4* xr = (const float4*)(sx + tt * 64);
    float a0 = 0.0f, a1 = 0.0f, a2 = 0.0f, a3 = 0.0f;
#define XSTEP(j) { float4 hv = xr[j]; \
    a0 = fmaf(w##j.x, hv.x, a0); a1 = fmaf(w##j.y, hv.y, a1); \
    a2 = fmaf(w##j.z, hv.z, a2); a3 = fmaf(w##j.w, hv.w, a3); }
    XSTEP(0) XSTEP(1) XSTEP(2) XSTEP(3) XSTEP(4) XSTEP(5) XSTEP(6) XSTEP(7)
    XSTEP(8) XSTEP(9) XSTEP(10) XSTEP(11) XSTEP(12) XSTEP(13) XSTEP(14) XSTEP(15)
#undef XSTEP
    dst[(size_t)tt * 512] = (a0 + a1) + (a2 + a3) + bias;
  }
}

// Kernel 2: full recurrence, one block per batch element, 1024 threads.
// LDS-PIPE REDUCTION RETILE (the one change vs round-1/5's 330us):
//   R8's ds_add regression calibrated LDS throughput (~2.7cyc/op saturated);
//   round-1 issues ~176 LDS ops/step (128 uniform b128 Phase-A reads + 32
//   partial writes + 16 GSUM) ≈ the ~2000cyc/step gap -> LDS-pipe-bound.
//   New tiling: wave w owns K-slice k=w>>1 (16 floats -> 4 uniform b128
//   reads, was 8) and gate-half (w&1); lane owns 4 contiguous gates (ONE
//   float4 sh_part write). LDS ops/step: 176 -> ~112. Register footprint
//   clamped to round-1's (16 named float4 weights, 4 scalar accs) — round
//   6's attempt at this died of scratch spill (WRITE_SIZE 3056), tripwire
//   this round: WRITE_SIZE must stay ~1.3MB.
//
// DELTA CANCELLATION (unchanged):
//   s[t] = a + d[t]; delta = a + top5(d)[4] + EPS  =>  w[t] = d[t]-t5v4-EPS
//   independent of a. Sparse attention = 4 register-indexed LDS row gathers
//   whose addresses are known from the PREVIOUS step (prefetched before S1).
//   Raw-score path (rem<=5) kept as a 5-step special case.
__global__
__attribute__((amdgpu_flat_work_group_size(1024, 1024), amdgpu_waves_per_eu(4, 4)))
void lstm_attn(
    const float* __restrict__ xw, const float* __restrict__ W_hh,
    const float* __restrict__ w_t, float* __restrict__ out)
{
  const int b   = blockIdx.x;
  const int tid = threadIdx.x;
  const int l   = tid & 63;       // lane
  const int wid = tid >> 6;
  const int k   = wid >> 1;       // K-slice 0..7 (16 floats), wave-uniform
  const int g0  = ((wid & 1) << 8) + (l << 2);   // 4 gates g0..g0+3

  __shared__ float ho[257 * 128];     // fp32 h history (131584 B)
  __shared__ float sh_part[8 * 512];  // gate partials [k][gate] (16 KB)
  __shared__ float sh_d[8];           // d[t] cache, only needed for t<5

  // one-time weight load: 4 gates x 4 float4 = 16 named float4 (as round 1)
  const float4* p0 = (const float4*)(W_hh + (size_t)(g0    ) * 128 + (k << 4));
  const float4* p1 = (const float4*)(W_hh + (size_t)(g0 + 1) * 128 + (k << 4));
  const float4* p2 = (const float4*)(W_hh + (size_t)(g0 + 2) * 128 + (k << 4));
  const float4* p3 = (const float4*)(W_hh + (size_t)(g0 + 3) * 128 + (k << 4));
  float4 w0_0 = p0[0], w0_1 = p0[1], w0_2 = p0[2], w0_3 = p0[3];
  float4 w1_0 = p1[0], w1_1 = p1[1], w1_2 = p1[2], w1_3 = p1[3];
  float4 w2_0 = p2[0], w2_1 = p2[1], w2_2 = p2[2], w2_3 = p2[3];
  float4 w3_0 = p3[0], w3_1 = p3[1], w3_2 = p3[2], w3_3 = p3[3];

  // wave0 per-lane persistent state (h elements j0=2l, j1=2l+1)
  const int j0 = 2 * l, j1 = 2 * l + 1;
  float c0 = 0.0f, c1 = 0.0f;
  float wa0 = 0.0f, wa1 = 0.0f, wb0 = 0.0f, wb1 = 0.0f;
  // running top-5 of d with indices (replicated identically in all wave0 lanes)
  float t5v0 = 0.0f, t5v1 = NEGF, t5v2 = NEGF, t5v3 = NEGF, t5v4 = NEGF;
  int   t5i0 = 0, t5i1 = 0, t5i2 = 0, t5i3 = 0;
  // precomputed (at end of step i-1) normalized gather weights + LDS offsets
  float gn0 = 0.0f, gn1 = 0.0f, gn2 = 0.0f, gn3 = 0.0f;
  int   ofs0 = 0, ofs1 = 0, ofs2 = 0, ofs3 = 0;

  if (wid == 0) {
    wa0 = w_t[j0];       wa1 = w_t[j1];
    wb0 = w_t[128 + j0]; wb1 = w_t[128 + j1];
    *(float2*)(ho + j0) = make_float2(0.0f, 0.0f);   // h(-1) = 0 (row 0)
    __builtin_amdgcn_s_setprio(1);   // wave0 is always the barrier straggler
  }
  if (tid == 0) sh_d[0] = 0.0f;
  __syncthreads();   // one-time full sync

  const float* xwb = xw + (size_t)b * 256 * 512;
  float xc0 = 0.0f, xc1 = 0.0f, xc2 = 0.0f, xc3 = 0.0f;
  if (k == 0) {
    float4 t = *(const float4*)(xwb + g0);
    xc0 = t.x; xc1 = t.y; xc2 = t.z; xc3 = t.w;
  }

  for (int i = 0; i < 256; ++i) {
    const int rem = i + 1;
    float hn0 = 0.0f, hn1 = 0.0f;

    // ---- Phase A: 4 gate-partials (64 FMAs from resident fp32 weights) ----
    float a0 = xc0, a1 = xc1, a2 = xc2, a3 = xc3;
    if (k == 0 && i < 255) {          // prefetch next step's xw (stays in
      float4 t = *(const float4*)(xwb + (size_t)(i + 1) * 512 + g0);
      xc0 = t.x; xc1 = t.y; xc2 = t.z; xc3 = t.w;
    }
    const float4* hh4 = (const float4*)(ho + i * 128 + (k << 4));
#define KSTEP(kk) { float4 hv = hh4[kk]; \
    a0 = fmaf(w0_##kk.x, hv.x, a0); a0 = fmaf(w0_##kk.y, hv.y, a0); \
    a0 = fmaf(w0_##kk.z, hv.z, a0); a0 = fmaf(w0_##kk.w, hv.w, a0); \
    a1 = fmaf(w1_##kk.x, hv.x, a1); a1 = fmaf(w1_##kk.y, hv.y, a1); \
    a1 = fmaf(w1_##kk.z, hv.z, a1); a1 = fmaf(w1_##kk.w, hv.w, a1); \
    a2 = fmaf(w2_##kk.x, hv.x, a2); a2 = fmaf(w2_##kk.y, hv.y, a2); \
    a2 = fmaf(w2_##kk.z, hv.z, a2); a2 = fmaf(w2_##kk.w, hv.w, a2); \
    a3 = fmaf(w3_##kk.x, hv.x, a3); a3 = fmaf(w3_##kk.y, hv.y, a3); \
    a3 = fmaf(w3_##kk.z, hv.z, a3); a3 = fmaf(w3_##kk.w, hv.w, a3); }
    KSTEP(0) KSTEP(1) KSTEP(2) KSTEP(3)
#undef KSTEP
    *(float4*)(sh_part + (k << 9) + g0) = make_float4(a0, a1, a2, a3);

    // gather prefetch: addresses known from previous step's top-5; ho rows
    // are append-only so reading before the barrier is race-free.
    float2 hv0, hv1, hv2, hv3;
    if (wid == 0 && i >= 5) {
      hv0 = *(const float2*)(ho + ofs0);
      hv1 = *(const float2*)(ho + ofs1);
      hv2 = *(const float2*)(ho + ofs2);
      hv3 = *(const float2*)(ho + ofs3);
    }
    RAWBAR();                                             // S1

    if (wid == 0) {
      // ---- Phase B: LSTM cell (2 elements/lane), 8-slice reduction ----
#define GSUM(base) ({ \
      float2 x0 = ((const float2*)(sh_part          + (base)))[l]; \
      float2 x1 = ((const float2*)(sh_part +  512   + (base)))[l]; \
      float2 x2 = ((const float2*)(sh_part + 1024   + (base)))[l]; \
      float2 x3 = ((const float2*)(sh_part + 1536   + (base)))[l]; \
      float2 x4 = ((const float2*)(sh_part + 2048   + (base)))[l]; \
      float2 x5 = ((const float2*)(sh_part + 2560   + (base)))[l]; \
      float2 x6 = ((const float2*)(sh_part + 3072   + (base)))[l]; \
      float2 x7 = ((const float2*)(sh_part + 3584   + (base)))[l]; \
      float2 r; \
      r.x = ((x0.x + x1.x) + (x2.x + x3.x)) + ((x4.x + x5.x) + (x6.x + x7.x)); \
      r.y = ((x0.y + x1.y) + (x2.y + x3.y)) + ((x4.y + x5.y) + (x6.y + x7.y)); \
      r; })
      float2 Pi = GSUM(0), Pf = GSUM(128), Pg = GSUM(256), Po = GSUM(384);
#undef GSUM
      c0 = fsigmoid(Pf.x) * c0 + fsigmoid(Pi.x) * ftanh(Pg.x);
      c1 = fsigmoid(Pf.y) * c1 + fsigmoid(Pi.y) * ftanh(Pg.y);
      float hc0 = fsigmoid(Po.x) * ftanh(c0);
      float hc1 = fsigmoid(Po.y) * ftanh(c1);

      float at0, at1;
      if (i >= 5) {
        // ---- sparse attention: 4 pre-fetched rows, register weights ----
        at0 = gn0 * hv0.x;            at1 = gn0 * hv0.y;
        at0 = fmaf(gn1, hv1.x, at0);  at1 = fmaf(gn1, hv1.y, at1);
        at0 = fmaf(gn2, hv2.x, at0);  at1 = fmaf(gn2, hv2.y, at1);
        at0 = fmaf(gn3, hv3.x, at0);  at1 = fmaf(gn3, hv3.y, at1);
      } else {
        // ---- rem<=5: attn weights are RAW scores s = a + d[t], no norm ----
        float a = wave_allsum(ftanh(hc0) * wa0 + ftanh(hc1) * wa1);
        at0 = 0.0f; at1 = 0.0f;
        for (int t = 0; t <= i; ++t) {
          float s = a + sh_d[t];
          float2 hv = *(const float2*)(ho + t * 128 + j0);
          at0 = fmaf(s, hv.x, at0);
          at1 = fmaf(s, hv.y, at1);
        }
      }
      hn0 = hc0 + at0; hn1 = hc1 + at1;
      *(float2*)(ho + rem * 128 + j0) = make_float2(hn0, hn1);
      if (i == 255) {
        out[b * 128 + j0] = at0; out[b * 128 + j1] = at1;   // attn_c
        // attn_w: zero except at the <=4 above-threshold top-5 indices
        #pragma unroll
        for (int m = 0; m < 4; ++m) {
          int t = l + 64 * m;
          float val = 0.0f;
          if (t == t5i0) val = gn0;
          if (t == t5i1) val = gn1;
          if (t == t5i2) val = gn2;
          if (t == t5i3) val = gn3;
          out[4096 + b * 256 + t] = val;
        }
      }
    }
    RAWBAR();                                             // S2

    // ---- tail (off critical path: overlaps other waves' next Phase A) ----
    if (wid == 0 && i < 255) {
      float dn = wave_allsum(ftanh(hn0) * wb0 + ftanh(hn1) * wb1);
      if (l == 0 && i < 4) sh_d[rem] = dn;   // only raw-score steps read it
      // replicated top-5 (value,index) insert — identical in every lane
      float v = dn; int vi = rem;
      if (v > t5v0) { float tv = t5v0; int ti = t5i0; t5v0 = v; t5i0 = vi; v = tv; vi = ti; }
      if (v > t5v1) { float tv = t5v1; int ti = t5i1; t5v1 = v; t5i1 = vi; v = tv; vi = ti; }
      if (v > t5v2) { float tv = t5v2; int ti = t5i2; t5v2 = v; t5i2 = vi; v = tv; vi = ti; }
      if (v > t5v3) { float tv = t5v3; int ti = t5i3; t5v3 = v; t5i3 = vi; v = tv; vi = ti; }
      if (v > t5v4) { t5v4 = v; }
      // next step's normalized gather weights + offsets (delta cancellation:
      // w[t] = d[t] - t5v4 - EPS, nonzero only among top-4)
      float g0f = fmaxf(t5v0 - t5v4 - EPSF, 0.0f);
      float g1f = fmaxf(t5v1 - t5v4 - EPSF, 0.0f);
      float g2f = fmaxf(t5v2 - t5v4 - EPSF, 0.0f);
      float g3f = fmaxf(t5v3 - t5v4 - EPSF, 0.0f);
      float inv = 1.0f / (((g0f + g1f) + (g2f + g3f)) + EPSF);
      gn0 = g0f * inv; gn1 = g1f * inv; gn2 = g2f * inv; gn3 = g3f * inv;
      ofs0 = (t5i0 << 7) + j0; ofs1 = (t5i1 << 7) + j0;
      ofs2 = (t5i2 << 7) + j0; ofs3 = (t5i3 << 7) + j0;
    }
  }
}

extern "C" void kernel_launch(void* const* d_in, const int* in_sizes, int n_in,
                              void* d_out, int out_size, void* d_ws, size_t ws_size,
                              hipStream_t stream) {
  const float* x    = (const float*)d_in[0];  // (32,256,64)
  const float* W_ih = (const float*)d_in[1];  // (512,64)
  const float* W_hh = (const float*)d_in[2];  // (512,128)
  const float* b_ih = (const float*)d_in[3];  // (512,)
  const float* b_hh = (const float*)d_in[4];  // (512,)
  const float* w_t  = (const float*)d_in[5];  // (256,1)
  float* out = (float*)d_out;                 // [0:4096) attn_c, [4096:12288) attn_w

  float* xw = (float*)d_ws;                   // 32*256*512 fp32 = 16 MB

  xw_kernel<<<dim3(8, 32), 512, 0, stream>>>(x, W_ih, b_ih, b_hh, xw);
  lstm_attn<<<dim3(32), 1024, 0, stream>>>(xw, W_hh, w_t, out);
}

// Round 10
// 659.004 us; speedup vs baseline: 1.4994x; 1.0424x over previous
//
#include <hip/hip_runtime.h>
#include <hip/hip_fp16.h>
#include <math.h>

#define NEGF -1000000000.0f
#define EPSF 1e-7f

// B=32, T=256, IN=64, H=128, 4H=512, TOP_K=5

// Raw barrier: LDS-only drain + s_barrier (keeps global prefetch in flight).
#define RAWBAR() asm volatile("s_waitcnt lgkmcnt(0)\n\ts_barrier" ::: "memory")

__device__ __forceinline__ float fsigmoid(float x) {
  return 1.0f / (1.0f + __expf(-x));               // overflow -> correct limit
}
__device__ __forceinline__ float ftanh(float x) {
  return 1.0f - 2.0f / (1.0f + __expf(2.0f * x));  // limits +-1: correct
}

// wave64 all-reduce sum via DPP (row_shr 1/2/4/8 + row_bcast 15/31), ~35 cyc.
__device__ __forceinline__ float wave_allsum(float v) {
#if __has_builtin(__builtin_amdgcn_update_dpp) && __has_builtin(__builtin_amdgcn_readlane)
  float f = v;
#define DPPSTEP(ctrl, rmask) { \
    int t = __builtin_amdgcn_update_dpp(0, __builtin_bit_cast(int, f), \
                                        ctrl, rmask, 0xf, true); \
    f += __builtin_bit_cast(float, t); }
  DPPSTEP(0x111, 0xf)   // row_shr:1
  DPPSTEP(0x112, 0xf)   // row_shr:2
  DPPSTEP(0x114, 0xf)   // row_shr:4
  DPPSTEP(0x118, 0xf)   // row_shr:8  -> lane15 of each row has row sum
  DPPSTEP(0x142, 0xa)   // row_bcast:15 into rows 1,3
  DPPSTEP(0x143, 0x8)   // row_bcast:31 into row 3 -> lane 63 = total
#undef DPPSTEP
  return __builtin_bit_cast(float,
      __builtin_amdgcn_readlane(__builtin_bit_cast(int, f), 63));
#else
  for (int off = 1; off < 64; off <<= 1) v += __shfl_xor(v, off, 64);
  return v;
#endif
}

// ONE fused kernel, 160 blocks x 1024 threads (all resident: 160 <= 256 CUs,
// 140KB LDS -> 1 block/CU).
//   blocks 0..31   : lstm recurrence for batch b = blockIdx.x (EXACT R1/R5
//                    structure, the proven 330us) consuming fp16 xw.
//   blocks 32..159 : xw producer. Block j-32 covers batch (j-32)>>2, token
//                    chunk ((j-32)&3)*64..+63. Publishes a device-scope
//                    release flag when its chunk is stored.
// Rationale: three different standalone xw kernels all cost ~83us (cold-clock
// + stream serialization, not compute: VALU floor ~3.4us). Running xw
// concurrently with the recurrence hides all but the initial chunk wait.
// No deadlock: lstm holds <=32 CUs; xw blocks always have free CUs and
// terminate unconditionally. Flags zeroed via hipMemsetAsync (capture-legal);
// stale-flag rocprof replays are benign (xw region persists, values equal).
__global__
__attribute__((amdgpu_flat_work_group_size(1024, 1024), amdgpu_waves_per_eu(4, 4)))
void lstm_attn(
    const float* __restrict__ x, const float* __restrict__ W_ih,
    const float* __restrict__ W_hh, const float* __restrict__ b_ih,
    const float* __restrict__ b_hh, const float* __restrict__ w_t,
    __half* __restrict__ xwh, int* __restrict__ flags,
    float* __restrict__ out)
{
  const int tid = threadIdx.x;

  // ================= xw producer role =================
  if (blockIdx.x >= 32) {
    const int j  = blockIdx.x - 32;           // 0..127
    const int bb = j >> 2;
    const int t0 = (j & 3) << 6;              // 64-token chunk
    const int g  = tid & 511;
    const int th = tid >> 9;                  // 32-token half

    const float4* wr = (const float4*)(W_ih + (size_t)g * 64);
    float4 w0 = wr[0],  w1 = wr[1],  w2 = wr[2],  w3 = wr[3],
           w4 = wr[4],  w5 = wr[5],  w6 = wr[6],  w7 = wr[7],
           w8 = wr[8],  w9 = wr[9],  w10 = wr[10], w11 = wr[11],
           w12 = wr[12], w13 = wr[13], w14 = wr[14], w15 = wr[15];
    const float bias = b_ih[g] + b_hh[g];

    const int tbase = bb * 256 + t0 + th * 32;
    __half* dst = xwh + (size_t)tbase * 512 + g;
    for (int tt = 0; tt < 32; ++tt) {
      // x row: wave-uniform address -> L1 broadcast loads
      const float4* xr = (const float4*)(x + (size_t)(tbase + tt) * 64);
      float a0 = 0.0f, a1 = 0.0f, a2 = 0.0f, a3 = 0.0f;
#define XSTEP(q) { float4 hv = xr[q]; \
      a0 = fmaf(w##q.x, hv.x, a0); a1 = fmaf(w##q.y, hv.y, a1); \
      a2 = fmaf(w##q.z, hv.z, a2); a3 = fmaf(w##q.w, hv.w, a3); }
      XSTEP(0) XSTEP(1) XSTEP(2) XSTEP(3) XSTEP(4) XSTEP(5) XSTEP(6) XSTEP(7)
      XSTEP(8) XSTEP(9) XSTEP(10) XSTEP(11) XSTEP(12) XSTEP(13) XSTEP(14) XSTEP(15)
#undef XSTEP
      dst[(size_t)tt * 512] = __float2half((a0 + a1) + (a2 + a3) + bias);
    }
    __syncthreads();
    if (tid == 0) {
      __threadfence();                         // make stores visible (agent)
      __hip_atomic_store(&flags[j], 1, __ATOMIC_RELEASE,
                         __HIP_MEMORY_SCOPE_AGENT);
    }
    return;
  }

  // ================= lstm role (R1/R5 structure verbatim) =================
  const int b   = blockIdx.x;
  const int l   = tid & 63;       // lane
  const int wid = tid >> 6;
  const int p   = tid & 255;      // gate-pair id
  const int q   = tid >> 8;       // K-chunk 0..3 (wave-uniform)
  const int gA  = p;
  const int gB  = p + 256;

  __shared__ float ho[257 * 128];     // fp32 h history (131584 B)
  __shared__ float sh_part[4 * 512];  // gate partials [q][gate] (8 KB)
  __shared__ float sh_d[8];           // d[t] cache, only needed for t<5

  // one-time weight load: 16 named float4
  const float4* pA = (const float4*)(W_hh + (size_t)gA * 128 + (q << 5));
  const float4* pB = (const float4*)(W_hh + (size_t)gB * 128 + (q << 5));
  float4 wA0 = pA[0], wA1 = pA[1], wA2 = pA[2], wA3 = pA[3],
         wA4 = pA[4], wA5 = pA[5], wA6 = pA[6], wA7 = pA[7];
  float4 wB0 = pB[0], wB1 = pB[1], wB2 = pB[2], wB3 = pB[3],
         wB4 = pB[4], wB5 = pB[5], wB6 = pB[6], wB7 = pB[7];

  // wave0 per-lane persistent state (h elements j0=2l, j1=2l+1)
  const int j0 = 2 * l, j1 = 2 * l + 1;
  float c0 = 0.0f, c1 = 0.0f;
  float wa0 = 0.0f, wa1 = 0.0f, wb0 = 0.0f, wb1 = 0.0f;
  float t5v0 = 0.0f, t5v1 = NEGF, t5v2 = NEGF, t5v3 = NEGF, t5v4 = NEGF;
  int   t5i0 = 0, t5i1 = 0, t5i2 = 0, t5i3 = 0;
  float gn0 = 0.0f, gn1 = 0.0f, gn2 = 0.0f, gn3 = 0.0f;
  int   ofs0 = 0, ofs1 = 0, ofs2 = 0, ofs3 = 0;

  if (wid == 0) {
    wa0 = w_t[j0];       wa1 = w_t[j1];
    wb0 = w_t[128 + j0]; wb1 = w_t[128 + j1];
    *(float2*)(ho + j0) = make_float2(0.0f, 0.0f);   // h(-1) = 0 (row 0)
    __builtin_amdgcn_s_setprio(1);   // wave0 is always the barrier straggler
  }
  if (tid == 0) sh_d[0] = 0.0f;
  __syncthreads();   // one-time full sync

  // wait for a 64-token xw chunk (tid0 spins on release flag, then barrier)
#define WAITCHUNK(c) { \
    if (tid == 0) { \
      while (__hip_atomic_load(&flags[(b << 2) + (c)], __ATOMIC_ACQUIRE, \
                               __HIP_MEMORY_SCOPE_AGENT) == 0) \
        __builtin_amdgcn_s_sleep(8); \
    } \
    __syncthreads(); }

  WAITCHUNK(0)

  const __half* xwb = xwh + (size_t)b * 256 * 512;
  float xcurA = 0.0f, xcurB = 0.0f;
  if (q == 0) {
    xcurA = __half2float(xwb[gA]);
    xcurB = __half2float(xwb[gB]);
  }

  for (int i = 0; i < 256; ++i) {
    const int rem = i + 1;
    float hn0 = 0.0f, hn1 = 0.0f;

    if ((i & 63) == 63 && i < 255) WAITCHUNK((i + 1) >> 6)

    // ---- Phase A: gate partials (64 FMAs from resident fp32 weights) ----
    float aA0 = xcurA, aA1 = 0.0f, aB0 = xcurB, aB1 = 0.0f;
    if (q == 0 && i < 255) {          // prefetch next step's xw
      xcurA = __half2float(xwb[(size_t)(i + 1) * 512 + gA]);
      xcurB = __half2float(xwb[(size_t)(i + 1) * 512 + gB]);
    }
    const float4* hh4 = (const float4*)(ho + i * 128 + (q << 5));
#define LSTEP(j) { float4 hv = hh4[j]; \
    aA0 = fmaf(wA##j.x, hv.x, aA0); aA1 = fmaf(wA##j.y, hv.y, aA1); \
    aA0 = fmaf(wA##j.z, hv.z, aA0); aA1 = fmaf(wA##j.w, hv.w, aA1); \
    aB0 = fmaf(wB##j.x, hv.x, aB0); aB1 = fmaf(wB##j.y, hv.y, aB1); \
    aB0 = fmaf(wB##j.z, hv.z, aB0); aB1 = fmaf(wB##j.w, hv.w, aB1); }
    LSTEP(0) LSTEP(1) LSTEP(2) LSTEP(3) LSTEP(4) LSTEP(5) LSTEP(6) LSTEP(7)
#undef LSTEP
    sh_part[(q << 9) + gA] = aA0 + aA1;
    sh_part[(q << 9) + gB] = aB0 + aB1;

    // gather prefetch: addresses known from previous step's top-5
    float2 hv0, hv1, hv2, hv3;
    if (wid == 0 && i >= 5) {
      hv0 = *(const float2*)(ho + ofs0);
      hv1 = *(const float2*)(ho + ofs1);
      hv2 = *(const float2*)(ho + ofs2);
      hv3 = *(const float2*)(ho + ofs3);
    }
    RAWBAR();                                             // S1

    if (wid == 0) {
      // ---- Phase B: LSTM cell (2 elements/lane) ----
#define GSUM(base) ({ \
      float2 x0 = ((const float2*)(sh_part        + (base)))[l]; \
      float2 x1 = ((const float2*)(sh_part +  512 + (base)))[l]; \
      float2 x2 = ((const float2*)(sh_part + 1024 + (base)))[l]; \
      float2 x3 = ((const float2*)(sh_part + 1536 + (base)))[l]; \
      float2 r; r.x = (x0.x + x1.x) + (x2.x + x3.x); \
      r.y = (x0.y + x1.y) + (x2.y + x3.y); r; })
      float2 Pi = GSUM(0), Pf = GSUM(128), Pg = GSUM(256), Po = GSUM(384);
#undef GSUM
      c0 = fsigmoid(Pf.x) * c0 + fsigmoid(Pi.x) * ftanh(Pg.x);
      c1 = fsigmoid(Pf.y) * c1 + fsigmoid(Pi.y) * ftanh(Pg.y);
      float hc0 = fsigmoid(Po.x) * ftanh(c0);
      float hc1 = fsigmoid(Po.y) * ftanh(c1);

      float at0, at1;
      if (i >= 5) {
        at0 = gn0 * hv0.x;            at1 = gn0 * hv0.y;
        at0 = fmaf(gn1, hv1.x, at0);  at1 = fmaf(gn1, hv1.y, at1);
        at0 = fmaf(gn2, hv2.x, at0);  at1 = fmaf(gn2, hv2.y, at1);
        at0 = fmaf(gn3, hv3.x, at0);  at1 = fmaf(gn3, hv3.y, at1);
      } else {
        // rem<=5: attn weights are RAW scores s = a + d[t], no norm
        float a = wave_allsum(ftanh(hc0) * wa0 + ftanh(hc1) * wa1);
        at0 = 0.0f; at1 = 0.0f;
        for (int t = 0; t <= i; ++t) {
          float s = a + sh_d[t];
          float2 hv = *(const float2*)(ho + t * 128 + j0);
          at0 = fmaf(s, hv.x, at0);
          at1 = fmaf(s, hv.y, at1);
        }
      }
      hn0 = hc0 + at0; hn1 = hc1 + at1;
      *(float2*)(ho + rem * 128 + j0) = make_float2(hn0, hn1);
      if (i == 255) {
        out[b * 128 + j0] = at0; out[b * 128 + j1] = at1;   // attn_c
        #pragma unroll
        for (int m = 0; m < 4; ++m) {
          int t = l + 64 * m;
          float val = 0.0f;
          if (t == t5i0) val = gn0;
          if (t == t5i1) val = gn1;
          if (t == t5i2) val = gn2;
          if (t == t5i3) val = gn3;
          out[4096 + b * 256 + t] = val;
        }
      }
    }
    RAWBAR();                                             // S2

    // ---- tail (off critical path) ----
    if (wid == 0 && i < 255) {
      float dn = wave_allsum(ftanh(hn0) * wb0 + ftanh(hn1) * wb1);
      if (l == 0 && i < 4) sh_d[rem] = dn;
      float v = dn; int vi = rem;
      if (v > t5v0) { float tv = t5v0; int ti = t5i0; t5v0 = v; t5i0 = vi; v = tv; vi = ti; }
      if (v > t5v1) { float tv = t5v1; int ti = t5i1; t5v1 = v; t5i1 = vi; v = tv; vi = ti; }
      if (v > t5v2) { float tv = t5v2; int ti = t5i2; t5v2 = v; t5i2 = vi; v = tv; vi = ti; }
      if (v > t5v3) { float tv = t5v3; int ti = t5i3; t5v3 = v; t5i3 = vi; v = tv; vi = ti; }
      if (v > t5v4) { t5v4 = v; }
      float g0 = fmaxf(t5v0 - t5v4 - EPSF, 0.0f);
      float g1 = fmaxf(t5v1 - t5v4 - EPSF, 0.0f);
      float g2 = fmaxf(t5v2 - t5v4 - EPSF, 0.0f);
      float g3 = fmaxf(t5v3 - t5v4 - EPSF, 0.0f);
      float inv = 1.0f / (((g0 + g1) + (g2 + g3)) + EPSF);
      gn0 = g0 * inv; gn1 = g1 * inv; gn2 = g2 * inv; gn3 = g3 * inv;
      ofs0 = (t5i0 << 7) + j0; ofs1 = (t5i1 << 7) + j0;
      ofs2 = (t5i2 << 7) + j0; ofs3 = (t5i3 << 7) + j0;
    }
  }
}

extern "C" void kernel_launch(void* const* d_in, const int* in_sizes, int n_in,
                              void* d_out, int out_size, void* d_ws, size_t ws_size,
                              hipStream_t stream) {
  const float* x    = (const float*)d_in[0];  // (32,256,64)
  const float* W_ih = (const float*)d_in[1];  // (512,64)
  const float* W_hh = (const float*)d_in[2];  // (512,128)
  const float* b_ih = (const float*)d_in[3];  // (512,)
  const float* b_hh = (const float*)d_in[4];  // (512,)
  const float* w_t  = (const float*)d_in[5];  // (256,1)
  float* out = (float*)d_out;                 // [0:4096) attn_c, [4096:12288) attn_w

  __half* xwh = (__half*)d_ws;                              // 8 MB fp16 xw
  int* flags  = (int*)((char*)d_ws + 8 * 1024 * 1024);      // 128 ints

  hipMemsetAsync(flags, 0, 128 * sizeof(int), stream);      // capture-legal
  lstm_attn<<<dim3(160), 1024, 0, stream>>>(x, W_ih, W_hh, b_ih, b_hh,
                                            w_t, xwh, flags, out);
}

// Round 11
// 398.138 us; speedup vs baseline: 2.4818x; 1.6552x over previous
//
#include <hip/hip_runtime.h>
#include <math.h>

#define NEGF -1000000000.0f
#define EPSF 1e-7f

// B=32, T=256, IN=64, H=128, 4H=512, TOP_K=5

// Raw barrier: LDS-only drain + s_barrier (keeps global prefetch in flight).
#define RAWBAR() asm volatile("s_waitcnt lgkmcnt(0)\n\ts_barrier" ::: "memory")

__device__ __forceinline__ float fsigmoid(float x) {
  return 1.0f / (1.0f + __expf(-x));               // overflow -> correct limit
}
__device__ __forceinline__ float ftanh(float x) {
  return 1.0f - 2.0f / (1.0f + __expf(2.0f * x));  // limits +-1: correct
}

// wave64 all-reduce sum via DPP (row_shr 1/2/4/8 + row_bcast 15/31), ~35 cyc.
__device__ __forceinline__ float wave_allsum(float v) {
#if __has_builtin(__builtin_amdgcn_update_dpp) && __has_builtin(__builtin_amdgcn_readlane)
  float f = v;
#define DPPSTEP(ctrl, rmask) { \
    int t = __builtin_amdgcn_update_dpp(0, __builtin_bit_cast(int, f), \
                                        ctrl, rmask, 0xf, true); \
    f += __builtin_bit_cast(float, t); }
  DPPSTEP(0x111, 0xf)   // row_shr:1
  DPPSTEP(0x112, 0xf)   // row_shr:2
  DPPSTEP(0x114, 0xf)   // row_shr:4
  DPPSTEP(0x118, 0xf)   // row_shr:8  -> lane15 of each row has row sum
  DPPSTEP(0x142, 0xa)   // row_bcast:15 into rows 1,3
  DPPSTEP(0x143, 0x8)   // row_bcast:31 into row 3 -> lane 63 = total
#undef DPPSTEP
  return __builtin_bit_cast(float,
      __builtin_amdgcn_readlane(__builtin_bit_cast(int, f), 63));
#else
  for (int off = 1; off < 64; off <<= 1) v += __shfl_xor(v, off, 64);
  return v;
#endif
}

// Kernel 1: xw[b][t][g] = x[b][t] . W_ih[g] + (b_ih[g]+b_hh[g])
// EXACT round-3 version (best measured two-kernel total: 412.7us).
__global__ __launch_bounds__(512) void xw_kernel(
    const float* __restrict__ x, const float* __restrict__ W_ih,
    const float* __restrict__ b_ih, const float* __restrict__ b_hh,
    float* __restrict__ xw)
{
  const int t0 = blockIdx.x * 32;
  const int b  = blockIdx.y;
  const int g  = threadIdx.x;

  __shared__ float sx[32 * 64];              // 8 KB
  ((float4*)sx)[threadIdx.x] =
      ((const float4*)(x + (size_t)(b * 256 + t0) * 64))[threadIdx.x];

  const float4* wr = (const float4*)(W_ih + (size_t)g * 64);
  float4 w0 = wr[0],  w1 = wr[1],  w2 = wr[2],  w3 = wr[3],
         w4 = wr[4],  w5 = wr[5],  w6 = wr[6],  w7 = wr[7],
         w8 = wr[8],  w9 = wr[9],  w10 = wr[10], w11 = wr[11],
         w12 = wr[12], w13 = wr[13], w14 = wr[14], w15 = wr[15];
  const float bias = b_ih[g] + b_hh[g];
  __syncthreads();

  float* dst = xw + (size_t)(b * 256 + t0) * 512 + g;
  for (int tt = 0; tt < 32; ++tt) {
    const float4* xr = (const float4*)(sx + tt * 64);
    float a0 = 0.0f, a1 = 0.0f, a2 = 0.0f, a3 = 0.0f;
#define XSTEP(j) { float4 hv = xr[j]; \
    a0 = fmaf(w##j.x, hv.x, a0); a1 = fmaf(w##j.y, hv.y, a1); \
    a2 = fmaf(w##j.z, hv.z, a2); a3 = fmaf(w##j.w, hv.w, a3); }
    XSTEP(0) XSTEP(1) XSTEP(2) XSTEP(3) XSTEP(4) XSTEP(5) XSTEP(6) XSTEP(7)
    XSTEP(8) XSTEP(9) XSTEP(10) XSTEP(11) XSTEP(12) XSTEP(13) XSTEP(14) XSTEP(15)
#undef XSTEP
    dst[(size_t)tt * 512] = (a0 + a1) + (a2 + a3) + bias;
  }
}

// Kernel 2: full recurrence, one block per batch element, 512 threads
// (8 waves, 2/SIMD). LDS-PIPE CUT, spill-safe this time:
//   m134 rates (b128 ~12cyc, b32 ~5.8cyc on the single LDS pipe) put R1's
//   step bill at ~1850cyc, dominated by 16 waves x 8 uniform b128 h-reads
//   (1540cyc). R6/R9 retiles died of SPILL at the 1024-thread 128-VGPR cap,
//   never falsifying the theory. Here: 8 waves at waves_per_eu(2,2) ->
//   256-VGPR cap. Thread (q=tid>>7, p=tid&127) owns all FOUR gate types of
//   element p (gates p,p+128,p+256,p+384) on K-chunk q: 128 weight floats
//   (32 float4) + 4 accs ~ 170 VGPR < 256. Phase-A b128 reads: 128 -> 64.
//   sh_part layout, GSUM, Phase B, delta-cancellation: byte-identical to R1.
//   Tripwire: WRITE_SIZE ~1.3MB (if ~3MB -> spilled again, path dead).
//
// DELTA CANCELLATION (unchanged):
//   s[t] = a + d[t]; delta = a + top5(d)[4] + EPS  =>  w[t] = d[t]-t5v4-EPS
//   independent of a. Sparse attention = 4 register-indexed LDS row gathers
//   whose addresses are known from the PREVIOUS step (prefetched before S1).
//   Raw-score path (rem<=5) kept as a 5-step special case.
__global__
__attribute__((amdgpu_flat_work_group_size(512, 512), amdgpu_waves_per_eu(2, 2)))
void lstm_attn(
    const float* __restrict__ xw, const float* __restrict__ W_hh,
    const float* __restrict__ w_t, float* __restrict__ out)
{
  const int b   = blockIdx.x;
  const int tid = threadIdx.x;
  const int l   = tid & 63;       // lane
  const int wid = tid >> 6;
  const int p   = tid & 127;      // element id (gate base)
  const int q   = tid >> 7;       // K-chunk 0..3 (uniform per wave pair)

  __shared__ float ho[257 * 128];     // fp32 h history (131584 B)
  __shared__ float sh_part[4 * 512];  // gate partials [q][gate] (8 KB)
  __shared__ float sh_d[8];           // d[t] cache, only needed for t<5

  // one-time weight load: 4 gate rows x 8 float4 = 32 named float4
  const float4* pI = (const float4*)(W_hh + (size_t)(p      ) * 128 + (q << 5));
  const float4* pF = (const float4*)(W_hh + (size_t)(p + 128) * 128 + (q << 5));
  const float4* pG = (const float4*)(W_hh + (size_t)(p + 256) * 128 + (q << 5));
  const float4* pO = (const float4*)(W_hh + (size_t)(p + 384) * 128 + (q << 5));
  float4 wI0 = pI[0], wI1 = pI[1], wI2 = pI[2], wI3 = pI[3],
         wI4 = pI[4], wI5 = pI[5], wI6 = pI[6], wI7 = pI[7];
  float4 wF0 = pF[0], wF1 = pF[1], wF2 = pF[2], wF3 = pF[3],
         wF4 = pF[4], wF5 = pF[5], wF6 = pF[6], wF7 = pF[7];
  float4 wG0 = pG[0], wG1 = pG[1], wG2 = pG[2], wG3 = pG[3],
         wG4 = pG[4], wG5 = pG[5], wG6 = pG[6], wG7 = pG[7];
  float4 wO0 = pO[0], wO1 = pO[1], wO2 = pO[2], wO3 = pO[3],
         wO4 = pO[4], wO5 = pO[5], wO6 = pO[6], wO7 = pO[7];

  // wave0 per-lane persistent state (h elements j0=2l, j1=2l+1)
  const int j0 = 2 * l, j1 = 2 * l + 1;
  float c0 = 0.0f, c1 = 0.0f;
  float wa0 = 0.0f, wa1 = 0.0f, wb0 = 0.0f, wb1 = 0.0f;
  float t5v0 = 0.0f, t5v1 = NEGF, t5v2 = NEGF, t5v3 = NEGF, t5v4 = NEGF;
  int   t5i0 = 0, t5i1 = 0, t5i2 = 0, t5i3 = 0;
  float gn0 = 0.0f, gn1 = 0.0f, gn2 = 0.0f, gn3 = 0.0f;
  int   ofs0 = 0, ofs1 = 0, ofs2 = 0, ofs3 = 0;

  if (wid == 0) {
    wa0 = w_t[j0];       wa1 = w_t[j1];
    wb0 = w_t[128 + j0]; wb1 = w_t[128 + j1];
    *(float2*)(ho + j0) = make_float2(0.0f, 0.0f);   // h(-1) = 0 (row 0)
    __builtin_amdgcn_s_setprio(1);   // wave0 is always the barrier straggler
  }
  if (tid == 0) sh_d[0] = 0.0f;
  __syncthreads();   // one-time full sync

  const float* xwb = xw + (size_t)b * 256 * 512;
  float xcI = 0.0f, xcF = 0.0f, xcG = 0.0f, xcO = 0.0f;
  if (q == 0) {
    xcI = xwb[p];       xcF = xwb[p + 128];
    xcG = xwb[p + 256]; xcO = xwb[p + 384];
  }

  for (int i = 0; i < 256; ++i) {
    const int rem = i + 1;
    float hn0 = 0.0f, hn1 = 0.0f;

    // ---- Phase A: 4 gate-partials (128 FMAs from resident fp32 weights) ----
    float aI = xcI, aF = xcF, aG = xcG, aO = xcO;
    if (q == 0 && i < 255) {          // prefetch next step's xw (stays in
      const float* xn = xwb + (size_t)(i + 1) * 512;     // flight over RAWBARs)
      xcI = xn[p];       xcF = xn[p + 128];
      xcG = xn[p + 256]; xcO = xn[p + 384];
    }
    const float4* hh4 = (const float4*)(ho + i * 128 + (q << 5));
#define KS(k) { float4 hv = hh4[k]; \
    aI = fmaf(wI##k.x, hv.x, aI); aI = fmaf(wI##k.y, hv.y, aI); \
    aI = fmaf(wI##k.z, hv.z, aI); aI = fmaf(wI##k.w, hv.w, aI); \
    aF = fmaf(wF##k.x, hv.x, aF); aF = fmaf(wF##k.y, hv.y, aF); \
    aF = fmaf(wF##k.z, hv.z, aF); aF = fmaf(wF##k.w, hv.w, aF); \
    aG = fmaf(wG##k.x, hv.x, aG); aG = fmaf(wG##k.y, hv.y, aG); \
    aG = fmaf(wG##k.z, hv.z, aG); aG = fmaf(wG##k.w, hv.w, aG); \
    aO = fmaf(wO##k.x, hv.x, aO); aO = fmaf(wO##k.y, hv.y, aO); \
    aO = fmaf(wO##k.z, hv.z, aO); aO = fmaf(wO##k.w, hv.w, aO); }
    KS(0) KS(1) KS(2) KS(3) KS(4) KS(5) KS(6) KS(7)
#undef KS
    {
      float* sp = sh_part + (q << 9) + p;
      sp[0]   = aI;
      sp[128] = aF;
      sp[256] = aG;
      sp[384] = aO;
    }

    // gather prefetch: addresses known from previous step's top-5; ho rows
    // are append-only so reading before the barrier is race-free.
    float2 hv0, hv1, hv2, hv3;
    if (wid == 0 && i >= 5) {
      hv0 = *(const float2*)(ho + ofs0);
      hv1 = *(const float2*)(ho + ofs1);
      hv2 = *(const float2*)(ho + ofs2);
      hv3 = *(const float2*)(ho + ofs3);
    }
    RAWBAR();                                             // S1

    if (wid == 0) {
      // ---- Phase B: LSTM cell (2 elements/lane) ----
#define GSUM(base) ({ \
      float2 x0 = ((const float2*)(sh_part        + (base)))[l]; \
      float2 x1 = ((const float2*)(sh_part +  512 + (base)))[l]; \
      float2 x2 = ((const float2*)(sh_part + 1024 + (base)))[l]; \
      float2 x3 = ((const float2*)(sh_part + 1536 + (base)))[l]; \
      float2 r; r.x = (x0.x + x1.x) + (x2.x + x3.x); \
      r.y = (x0.y + x1.y) + (x2.y + x3.y); r; })
      float2 Pi = GSUM(0), Pf = GSUM(128), Pg = GSUM(256), Po = GSUM(384);
#undef GSUM
      c0 = fsigmoid(Pf.x) * c0 + fsigmoid(Pi.x) * ftanh(Pg.x);
      c1 = fsigmoid(Pf.y) * c1 + fsigmoid(Pi.y) * ftanh(Pg.y);
      float hc0 = fsigmoid(Po.x) * ftanh(c0);
      float hc1 = fsigmoid(Po.y) * ftanh(c1);

      float at0, at1;
      if (i >= 5) {
        // ---- sparse attention: 4 pre-fetched rows, register weights ----
        at0 = gn0 * hv0.x;            at1 = gn0 * hv0.y;
        at0 = fmaf(gn1, hv1.x, at0);  at1 = fmaf(gn1, hv1.y, at1);
        at0 = fmaf(gn2, hv2.x, at0);  at1 = fmaf(gn2, hv2.y, at1);
        at0 = fmaf(gn3, hv3.x, at0);  at1 = fmaf(gn3, hv3.y, at1);
      } else {
        // ---- rem<=5: attn weights are RAW scores s = a + d[t], no norm ----
        float a = wave_allsum(ftanh(hc0) * wa0 + ftanh(hc1) * wa1);
        at0 = 0.0f; at1 = 0.0f;
        for (int t = 0; t <= i; ++t) {
          float s = a + sh_d[t];
          float2 hv = *(const float2*)(ho + t * 128 + j0);
          at0 = fmaf(s, hv.x, at0);
          at1 = fmaf(s, hv.y, at1);
        }
      }
      hn0 = hc0 + at0; hn1 = hc1 + at1;
      *(float2*)(ho + rem * 128 + j0) = make_float2(hn0, hn1);
      if (i == 255) {
        out[b * 128 + j0] = at0; out[b * 128 + j1] = at1;   // attn_c
        // attn_w: zero except at the <=4 above-threshold top-5 indices
        #pragma unroll
        for (int m = 0; m < 4; ++m) {
          int t = l + 64 * m;
          float val = 0.0f;
          if (t == t5i0) val = gn0;
          if (t == t5i1) val = gn1;
          if (t == t5i2) val = gn2;
          if (t == t5i3) val = gn3;
          out[4096 + b * 256 + t] = val;
        }
      }
    }
    RAWBAR();                                             // S2

    // ---- tail (off critical path: overlaps other waves' next Phase A) ----
    if (wid == 0 && i < 255) {
      float dn = wave_allsum(ftanh(hn0) * wb0 + ftanh(hn1) * wb1);
      if (l == 0 && i < 4) sh_d[rem] = dn;   // only raw-score steps read it
      // replicated top-5 (value,index) insert — identical in every lane
      float v = dn; int vi = rem;
      if (v > t5v0) { float tv = t5v0; int ti = t5i0; t5v0 = v; t5i0 = vi; v = tv; vi = ti; }
      if (v > t5v1) { float tv = t5v1; int ti = t5i1; t5v1 = v; t5i1 = vi; v = tv; vi = ti; }
      if (v > t5v2) { float tv = t5v2; int ti = t5i2; t5v2 = v; t5i2 = vi; v = tv; vi = ti; }
      if (v > t5v3) { float tv = t5v3; int ti = t5i3; t5v3 = v; t5i3 = vi; v = tv; vi = ti; }
      if (v > t5v4) { t5v4 = v; }
      // next step's normalized gather weights + offsets (delta cancellation:
      // w[t] = d[t] - t5v4 - EPS, nonzero only among top-4)
      float g0 = fmaxf(t5v0 - t5v4 - EPSF, 0.0f);
      float g1 = fmaxf(t5v1 - t5v4 - EPSF, 0.0f);
      float g2 = fmaxf(t5v2 - t5v4 - EPSF, 0.0f);
      float g3 = fmaxf(t5v3 - t5v4 - EPSF, 0.0f);
      float inv = 1.0f / (((g0 + g1) + (g2 + g3)) + EPSF);
      gn0 = g0 * inv; gn1 = g1 * inv; gn2 = g2 * inv; gn3 = g3 * inv;
      ofs0 = (t5i0 << 7) + j0; ofs1 = (t5i1 << 7) + j0;
      ofs2 = (t5i2 << 7) + j0; ofs3 = (t5i3 << 7) + j0;
    }
  }
}

extern "C" void kernel_launch(void* const* d_in, const int* in_sizes, int n_in,
                              void* d_out, int out_size, void* d_ws, size_t ws_size,
                              hipStream_t stream) {
  const float* x    = (const float*)d_in[0];  // (32,256,64)
  const float* W_ih = (const float*)d_in[1];  // (512,64)
  const float* W_hh = (const float*)d_in[2];  // (512,128)
  const float* b_ih = (const float*)d_in[3];  // (512,)
  const float* b_hh = (const float*)d_in[4];  // (512,)
  const float* w_t  = (const float*)d_in[5];  // (256,1)
  float* out = (float*)d_out;                 // [0:4096) attn_c, [4096:12288) attn_w

  float* xw = (float*)d_ws;                   // 32*256*512 fp32 = 16 MB

  xw_kernel<<<dim3(8, 32), 512, 0, stream>>>(x, W_ih, b_ih, b_hh, xw);
  lstm_attn<<<dim3(32), 512, 0, stream>>>(xw, W_hh, w_t, out);
}